// Round 1
// baseline (125.018 us; speedup 1.0000x reference)
//
#include <hip/hip_runtime.h>

#define NN 8192
#define KDIM 256
#define FDIM 64
#define SLOPEC 0.2f

typedef __attribute__((ext_vector_type(8))) short bf16x8;
typedef __attribute__((ext_vector_type(4))) float f32x4;

__device__ __forceinline__ unsigned short f2bf(float x) {
    union { float f; unsigned u; } v; v.f = x;
    unsigned r = v.u + 0x7FFFu + ((v.u >> 16) & 1u);
    return (unsigned short)(r >> 16);
}

__device__ __forceinline__ float wred64(float v) {
    v += __shfl_xor(v, 1);
    v += __shfl_xor(v, 2);
    v += __shfl_xor(v, 4);
    v += __shfl_xor(v, 8);
    v += __shfl_xor(v, 16);
    v += __shfl_xor(v, 32);
    return v;
}

// Phase 1: Wh = h@W (f32 accum), write WhT as bf16 [FDIM][NN], f_i = Wh@a[:64], f_j = Wh@a[64:]
// block = 256 thr (4 waves), 16 rows/block; wave rg handles rows i0+rg*4..+3, lane = f.
__global__ __launch_bounds__(256) void gat_phase1(
    const float* __restrict__ h, const float* __restrict__ W,
    const float* __restrict__ a, unsigned short* __restrict__ whT,
    float* __restrict__ fi, float* __restrict__ fj)
{
    __shared__ unsigned short wht_s[FDIM][20];  // padded: 2B stores land 2-way max
    const int tid = threadIdx.x;
    const int f  = tid & 63;
    const int rg = tid >> 6;
    const int i0 = blockIdx.x << 4;

    const float* __restrict__ h0 = h + (size_t)(i0 + rg * 4) * KDIM;
    const float* __restrict__ h1 = h0 + KDIM;
    const float* __restrict__ h2 = h0 + 2 * KDIM;
    const float* __restrict__ h3 = h0 + 3 * KDIM;

    float acc0 = 0.f, acc1 = 0.f, acc2 = 0.f, acc3 = 0.f;
    #pragma unroll 4
    for (int k4 = 0; k4 < KDIM / 4; ++k4) {
        const float4 r0 = *(const float4*)(h0 + k4 * 4);  // lane-uniform broadcast
        const float4 r1 = *(const float4*)(h1 + k4 * 4);
        const float4 r2 = *(const float4*)(h2 + k4 * 4);
        const float4 r3 = *(const float4*)(h3 + k4 * 4);
        const float w0 = W[(k4 * 4 + 0) * FDIM + f];      // coalesced
        const float w1 = W[(k4 * 4 + 1) * FDIM + f];
        const float w2 = W[(k4 * 4 + 2) * FDIM + f];
        const float w3 = W[(k4 * 4 + 3) * FDIM + f];
        acc0 += r0.x * w0 + r0.y * w1 + r0.z * w2 + r0.w * w3;
        acc1 += r1.x * w0 + r1.y * w1 + r1.z * w2 + r1.w * w3;
        acc2 += r2.x * w0 + r2.y * w1 + r2.z * w2 + r2.w * w3;
        acc3 += r3.x * w0 + r3.y * w1 + r3.z * w2 + r3.w * w3;
    }

    const int r0i = rg * 4;
    wht_s[f][r0i + 0] = f2bf(acc0);
    wht_s[f][r0i + 1] = f2bf(acc1);
    wht_s[f][r0i + 2] = f2bf(acc2);
    wht_s[f][r0i + 3] = f2bf(acc3);

    const float aL = a[f];
    const float aR = a[FDIM + f];
    float s;
    s = wred64(acc0 * aL); if (f == 0) fi[i0 + r0i + 0] = s;
    s = wred64(acc1 * aL); if (f == 0) fi[i0 + r0i + 1] = s;
    s = wred64(acc2 * aL); if (f == 0) fi[i0 + r0i + 2] = s;
    s = wred64(acc3 * aL); if (f == 0) fi[i0 + r0i + 3] = s;
    s = wred64(acc0 * aR); if (f == 0) fj[i0 + r0i + 0] = s;
    s = wred64(acc1 * aR); if (f == 0) fj[i0 + r0i + 1] = s;
    s = wred64(acc2 * aR); if (f == 0) fj[i0 + r0i + 2] = s;
    s = wred64(acc3 * aR); if (f == 0) fj[i0 + r0i + 3] = s;

    __syncthreads();
    // write WhT[f][i0..i0+15] bf16, 8B per thread
    const int fr = tid >> 2, c = tid & 3;
    ushort4 v;
    v.x = wht_s[fr][c * 4 + 0];
    v.y = wht_s[fr][c * 4 + 1];
    v.z = wht_s[fr][c * 4 + 2];
    v.w = wht_s[fr][c * 4 + 3];
    *(ushort4*)(whT + (size_t)fr * NN + i0 + c * 4) = v;
}

// Phase 2: per block 16 rows; out_i = (sum_j p_ij Wh_j) / (sum_j p_ij),
// p_ij = adj ? exp(lrelu(f_i+f_j)) : 0.  MFMA 16x16x32 bf16; 4 waves interleave j.
__global__ __launch_bounds__(256) void gat_phase2(
    const int* __restrict__ adj, const unsigned short* __restrict__ whT,
    const float* __restrict__ fi, const float* __restrict__ fjg,
    float* __restrict__ out)
{
    __shared__ float fj_s[NN];            // 32 KB
    __shared__ float red[4][16][FDIM];    // 16 KB
    __shared__ float zred[4][16];

    const int tid = threadIdx.x;
    const int w  = tid >> 6;
    const int l  = tid & 63;
    const int li = l & 15;   // MFMA A row / adj row within tile
    const int q  = l >> 4;   // k-quarter
    const int qo = q * 8;
    const int i0 = blockIdx.x << 4;

    for (int t = tid; t < NN / 4; t += 256)
        ((float4*)fj_s)[t] = ((const float4*)fjg)[t];
    __syncthreads();

    const float f_i = fi[i0 + li];
    const int* __restrict__ adjrow = adj + (size_t)(i0 + li) * NN;
    const unsigned short* __restrict__ wrow0 = whT + (size_t)(0 * 16 + li) * NN;
    const unsigned short* __restrict__ wrow1 = whT + (size_t)(1 * 16 + li) * NN;
    const unsigned short* __restrict__ wrow2 = whT + (size_t)(2 * 16 + li) * NN;
    const unsigned short* __restrict__ wrow3 = whT + (size_t)(3 * 16 + li) * NN;

    f32x4 acc0 = {0.f, 0.f, 0.f, 0.f};
    f32x4 acc1 = {0.f, 0.f, 0.f, 0.f};
    f32x4 acc2 = {0.f, 0.f, 0.f, 0.f};
    f32x4 acc3 = {0.f, 0.f, 0.f, 0.f};
    float z = 0.f;

    // wave w owns K-steps t = w + 4s (j0 = 32t); 64 steps per wave.
    auto step = [&](int s, const int4& c0, const int4& c1) {
        const int jb = (w + 4 * s) * 32;
        const int jl = jb + qo;
        const float4 fj0 = *(const float4*)(fj_s + jl);
        const float4 fj1 = *(const float4*)(fj_s + jl + 4);
        // b-fragments: B[k][col] = WhT[col_row][jb + qo + e]
        const bf16x8 b0 = *(const bf16x8*)(wrow0 + jl);
        const bf16x8 b1 = *(const bf16x8*)(wrow1 + jl);
        const bf16x8 b2 = *(const bf16x8*)(wrow2 + jl);
        const bf16x8 b3 = *(const bf16x8*)(wrow3 + jl);
        float e0 = f_i + fj0.x; e0 = fmaxf(e0, SLOPEC * e0);
        float e1 = f_i + fj0.y; e1 = fmaxf(e1, SLOPEC * e1);
        float e2 = f_i + fj0.z; e2 = fmaxf(e2, SLOPEC * e2);
        float e3 = f_i + fj0.w; e3 = fmaxf(e3, SLOPEC * e3);
        float e4 = f_i + fj1.x; e4 = fmaxf(e4, SLOPEC * e4);
        float e5 = f_i + fj1.y; e5 = fmaxf(e5, SLOPEC * e5);
        float e6 = f_i + fj1.z; e6 = fmaxf(e6, SLOPEC * e6);
        float e7 = f_i + fj1.w; e7 = fmaxf(e7, SLOPEC * e7);
        const float p0 = (c0.x > 0) ? __expf(e0) : 0.f;
        const float p1 = (c0.y > 0) ? __expf(e1) : 0.f;
        const float p2 = (c0.z > 0) ? __expf(e2) : 0.f;
        const float p3 = (c0.w > 0) ? __expf(e3) : 0.f;
        const float p4 = (c1.x > 0) ? __expf(e4) : 0.f;
        const float p5 = (c1.y > 0) ? __expf(e5) : 0.f;
        const float p6 = (c1.z > 0) ? __expf(e6) : 0.f;
        const float p7 = (c1.w > 0) ? __expf(e7) : 0.f;
        z += ((p0 + p1) + (p2 + p3)) + ((p4 + p5) + (p6 + p7));
        bf16x8 afrag;
        afrag[0] = (short)f2bf(p0);
        afrag[1] = (short)f2bf(p1);
        afrag[2] = (short)f2bf(p2);
        afrag[3] = (short)f2bf(p3);
        afrag[4] = (short)f2bf(p4);
        afrag[5] = (short)f2bf(p5);
        afrag[6] = (short)f2bf(p6);
        afrag[7] = (short)f2bf(p7);
        acc0 = __builtin_amdgcn_mfma_f32_16x16x32_bf16(afrag, b0, acc0, 0, 0, 0);
        acc1 = __builtin_amdgcn_mfma_f32_16x16x32_bf16(afrag, b1, acc1, 0, 0, 0);
        acc2 = __builtin_amdgcn_mfma_f32_16x16x32_bf16(afrag, b2, acc2, 0, 0, 0);
        acc3 = __builtin_amdgcn_mfma_f32_16x16x32_bf16(afrag, b3, acc3, 0, 0, 0);
    };

    // 2-deep software pipeline on adj loads (A = even steps, B = odd steps)
    int4 A0 = *(const int4*)(adjrow + ((w + 0) * 32) + qo);
    int4 A1 = *(const int4*)(adjrow + ((w + 0) * 32) + qo + 4);
    int4 B0 = *(const int4*)(adjrow + ((w + 4) * 32) + qo);
    int4 B1 = *(const int4*)(adjrow + ((w + 4) * 32) + qo + 4);
    for (int s = 0; s < 64; s += 2) {
        const int ja = (((w + 4 * (s + 2)) * 32) & (NN - 1)) + qo;
        const int4 nA0 = *(const int4*)(adjrow + ja);
        const int4 nA1 = *(const int4*)(adjrow + ja + 4);
        step(s, A0, A1);
        A0 = nA0; A1 = nA1;
        const int jbn = (((w + 4 * (s + 3)) * 32) & (NN - 1)) + qo;
        const int4 nB0 = *(const int4*)(adjrow + jbn);
        const int4 nB1 = *(const int4*)(adjrow + jbn + 4);
        step(s + 1, B0, B1);
        B0 = nB0; B1 = nB1;
    }

    // epilogue: cross-wave reduce + normalize
    #pragma unroll
    for (int r = 0; r < 4; ++r) {
        red[w][q * 4 + r][0 * 16 + li] = acc0[r];
        red[w][q * 4 + r][1 * 16 + li] = acc1[r];
        red[w][q * 4 + r][2 * 16 + li] = acc2[r];
        red[w][q * 4 + r][3 * 16 + li] = acc3[r];
    }
    z += __shfl_xor(z, 16);
    z += __shfl_xor(z, 32);
    if (q == 0) zred[w][li] = z;
    __syncthreads();

    const int f  = tid & 63;
    const int ig = tid >> 6;
    #pragma unroll
    for (int c = 0; c < 4; ++c) {
        const int i = c * 4 + ig;
        const float v = red[0][i][f] + red[1][i][f] + red[2][i][f] + red[3][i][f];
        const float zz = zred[0][i] + zred[1][i] + zred[2][i] + zred[3][i];
        out[(size_t)(i0 + i) * FDIM + f] = v / zz;
    }
}

extern "C" void kernel_launch(void* const* d_in, const int* in_sizes, int n_in,
                              void* d_out, int out_size, void* d_ws, size_t ws_size,
                              hipStream_t stream) {
    const float* h   = (const float*)d_in[0];
    const int*   adj = (const int*)d_in[1];
    const float* W   = (const float*)d_in[2];
    const float* a   = (const float*)d_in[3];
    float* out = (float*)d_out;

    unsigned short* whT = (unsigned short*)d_ws;                       // 1 MB
    float* fi = (float*)((char*)d_ws + (size_t)NN * FDIM * 2);         // 32 KB
    float* fj = fi + NN;                                               // 32 KB

    gat_phase1<<<NN / 16, 256, 0, stream>>>(h, W, a, whT, fi, fj);
    gat_phase2<<<NN / 16, 256, 0, stream>>>(adj, whT, fi, fj, out);
}